// Round 5
// baseline (670.365 us; speedup 1.0000x reference)
//
#include <hip/hip_runtime.h>

#define LOG2E 1.44269504088896340736f

__device__ __forceinline__ float fast_tanh(float v) {
    return 1.0f - 2.0f * __builtin_amdgcn_rcpf(1.0f + __builtin_amdgcn_exp2f(2.0f * LOG2E * v));
}

// Four waves per batch-pair (one gate each):
//   role 0: gate i (rows   0.. 63) — owns batch 0's c/h recurrence
//   role 1: gate f (rows  64..127) — owns batch 1's c/h recurrence
//   role 2: gate g (rows 128..191)
//   role 3: gate o (rows 192..255)
// Each lane holds one W_hh row (64 floats). R4 showed LLVM homes that array in
// AGPRs (VGPR_Count=48) and pays a v_accvgpr_read per FMA (~2x instr count).
// Fix: force VGPR class via inline-asm v_fmac with "v" constraints on every
// use, and pin the defs with empty-asm ties at load time.
__global__ void __launch_bounds__(256, 4)
lstm_fused(const float* __restrict__ x,      // [2048,512,1]
           const float* __restrict__ W_ih,   // [256,1]
           const float* __restrict__ W_hh,   // [256,64]
           const float* __restrict__ b_ih,   // [256]
           const float* __restrict__ b_hh,   // [256]
           const float* __restrict__ W_fc,   // [2,64]
           const float* __restrict__ b_fc,   // [2]
           float* __restrict__ out)          // [2048,2]
{
    constexpr int T = 512;
    __shared__ __align__(16) float hbuf[2][64];        // [batch][unit]
    __shared__ __align__(16) float exch[4][2][64];     // [gate][batch][unit]

    const int lane = threadIdx.x & 63;
    const int role = threadIdx.x >> 6;        // 0..3 == gate i,f,g,o
    const int b0   = blockIdx.x * 2;
    const int b1   = b0 + 1;

    // ---- W row for this (role, lane), pinned to arch VGPRs ----
    const int row = role * 64 + lane;
    float w[64];
    {
        const float* Wr = W_hh + (long)row * 64;
        #pragma unroll
        for (int j = 0; j < 64; j += 4) {
            *(float4*)&w[j] = *(const float4*)&Wr[j];
            // pin definitions to VGPR class (zero-instruction class tie)
            asm("" : "+v"(w[j]), "+v"(w[j + 1]), "+v"(w[j + 2]), "+v"(w[j + 3]));
        }
    }
    const float wx = W_ih[row];
    const float bs = b_ih[row] + b_hh[row];

    // Unified nonlinearity: n(v) = A + B * rcp(1 + exp2(k*v))
    //   sigmoid (i,f,o): k=-LOG2E,  A=0, B=1
    //   tanh    (g):     k=+2LOG2E, A=1, B=-2
    const float kR = (role == 2) ? (2.0f * LOG2E) : (-LOG2E);
    const float AR = (role == 2) ? 1.0f : 0.0f;
    const float BR = (role == 2) ? -2.0f : 1.0f;

    if (role == 0) {
        hbuf[0][lane] = 0.0f;
        hbuf[1][lane] = 0.0f;
    }
    __syncthreads();

    float c = 0.0f;     // cell state of own batch (roles 0,1 only)
    float hown = 0.0f;

    const float* x0p = x + (long)b0 * T;
    const float* x1p = x + (long)b1 * T;

    for (int tb = 0; tb < T; tb += 64) {
        // coalesced x chunk; per-step broadcast via readlane (uniform index)
        float xc0 = x0p[tb + lane];
        float xc1 = x1p[tb + lane];
        for (int tt = 0; tt < 64; ++tt) {
            float sx0 = __builtin_bit_cast(float,
                __builtin_amdgcn_readlane(__builtin_bit_cast(int, xc0), tt));
            float sx1 = __builtin_bit_cast(float,
                __builtin_amdgcn_readlane(__builtin_bit_cast(int, xc1), tt));

            float a0 = fmaf(sx0, wx, bs);
            float a1 = fmaf(sx1, wx, bs);

            // matvec over h: uniform-address b128 broadcast reads + asm FMAs
            const float4* hA = (const float4*)&hbuf[0][0];
            const float4* hB = (const float4*)&hbuf[1][0];
            #pragma unroll
            for (int jc = 0; jc < 16; ++jc) {
                float4 hv0 = hA[jc];
                float4 hv1 = hB[jc];
                #pragma unroll
                for (int u = 0; u < 4; ++u) {
                    const int j = jc * 4 + u;
                    asm("v_fmac_f32 %0, %1, %2"
                        : "+v"(a0) : "v"((&hv0.x)[u]), "v"(w[j]));
                    asm("v_fmac_f32 %0, %1, %2"
                        : "+v"(a1) : "v"((&hv1.x)[u]), "v"(w[j]));
                }
            }

            // this wave's gate nonlinearity for both batches
            float n0 = fmaf(BR, __builtin_amdgcn_rcpf(1.0f + __builtin_amdgcn_exp2f(kR * a0)), AR);
            float n1 = fmaf(BR, __builtin_amdgcn_rcpf(1.0f + __builtin_amdgcn_exp2f(kR * a1)), AR);

            exch[role][0][lane] = n0;
            exch[role][1][lane] = n1;
            __syncthreads();

            if (role < 2) {   // owner of batch `role`
                const float ig = exch[0][role][lane];
                const float fg = exch[1][role][lane];
                const float gg = exch[2][role][lane];
                const float og = exch[3][role][lane];
                c    = fmaf(fg, c, ig * gg);
                hown = og * fast_tanh(c);
                hbuf[role][lane] = hown;
            }
            __syncthreads();
        }
    }

    // ---- epilogue: out[b_own,:] = h_own @ W_fc.T + b_fc (roles 0,1 only) ----
    if (role < 2) {
        const int   bown = b0 + role;
        const float wc0  = W_fc[lane];
        const float wc1  = W_fc[64 + lane];
        float p0 = hown * wc0;
        float p1 = hown * wc1;
        #pragma unroll
        for (int off = 32; off > 0; off >>= 1) {
            p0 += __shfl_down(p0, off);
            p1 += __shfl_down(p1, off);
        }
        if (lane == 0) {
            out[bown * 2 + 0] = p0 + b_fc[0];
            out[bown * 2 + 1] = p1 + b_fc[1];
        }
    }
}

extern "C" void kernel_launch(void* const* d_in, const int* in_sizes, int n_in,
                              void* d_out, int out_size, void* d_ws, size_t ws_size,
                              hipStream_t stream) {
    const float* x    = (const float*)d_in[0];
    const float* W_ih = (const float*)d_in[1];
    const float* W_hh = (const float*)d_in[2];
    const float* b_ih = (const float*)d_in[3];
    const float* b_hh = (const float*)d_in[4];
    const float* W_fc = (const float*)d_in[5];
    const float* b_fc = (const float*)d_in[6];
    float* out = (float*)d_out;

    dim3 grid(1024);   // one batch-pair per block, 4 gate-waves per block
    dim3 block(256);
    hipLaunchKernelGGL(lstm_fused, grid, block, 0, stream,
                       x, W_ih, W_hh, b_ih, b_hh, W_fc, b_fc, out);
}

// Round 6
// 285.698 us; speedup vs baseline: 2.3464x; 2.3464x over previous
//
#include <hip/hip_runtime.h>

#define LOG2E 1.44269504088896340736f

typedef short    short8  __attribute__((ext_vector_type(8)));
typedef float    floatx4 __attribute__((ext_vector_type(4)));
typedef unsigned uintx4  __attribute__((ext_vector_type(4)));

__device__ __forceinline__ unsigned pk_bf16(float lo, float hi) {
    unsigned r;
    asm("v_cvt_pk_bf16_f32 %0, %1, %2" : "=v"(r) : "v"(lo), "v"(hi));
    return r;
}
__device__ __forceinline__ float fast_tanh(float v) {
    return 1.0f - 2.0f * __builtin_amdgcn_rcpf(1.0f + __builtin_amdgcn_exp2f(2.0f * LOG2E * v));
}

// MFMA LSTM: 256 blocks x 512 threads (8 waves). Block owns 8 batches.
// Per step: gates_raw[16,256] = h_bf16[16,64] @ W_hh^T (rows 8-15 zero pad)
//   wave w computes n-tiles {2w, 2w+1} via 4x mfma_f32_16x16x32_bf16
//   -> raw gates to LDS exch[g][b] -> owner thread (b=wave, u=lane) adds
//   x*W_ih+bias, nonlinearities, c/h update, writes h back as bf16 (swizzled).
__global__ void __launch_bounds__(512, 2)
lstm_mfma(const float* __restrict__ x,      // [2048,512]
          const float* __restrict__ W_ih,   // [256]
          const float* __restrict__ W_hh,   // [256,64]
          const float* __restrict__ b_ih,   // [256]
          const float* __restrict__ b_hh,   // [256]
          const float* __restrict__ W_fc,   // [2,64]
          const float* __restrict__ b_fc,   // [2]
          float* __restrict__ out)          // [2048,2]
{
    constexpr int T = 512;
    __shared__ unsigned hlds[16 * 32];   // h as bf16 pairs: row m, word kp^((m&7)<<2)
    __shared__ float    exch[256 * 9];   // raw gate partials [g][b], stride 9

    const int tid  = threadIdx.x;
    const int w    = tid >> 6;           // wave 0..7 (= owner batch b)
    const int lane = tid & 63;           // (= owner unit u)
    const int l15  = lane & 15;
    const int lq   = lane >> 4;
    const int b0   = blockIdx.x * 8;

    // zero-init h (incl. padding rows 8-15, which stay zero forever)
    hlds[tid >= 512 ? 0 : tid] = 0u;     // tid<512 always; 512 entries exactly
    // ---- B fragments: B[k][n] = W_hh[g][k], g = ntile*16 + l15 ----
    // lane l: col = l15, k = 32*f + 8*lq + e  (e=0..7, bf16 pairs in u32)
    short8 bf[2][2];
    #pragma unroll
    for (int j = 0; j < 2; ++j) {
        const int g = (2 * w + j) * 16 + l15;
        #pragma unroll
        for (int f = 0; f < 2; ++f) {
            const float* p = W_hh + g * 64 + 32 * f + 8 * lq;
            uintx4 uv;
            uv.x = pk_bf16(p[0], p[1]);
            uv.y = pk_bf16(p[2], p[3]);
            uv.z = pk_bf16(p[4], p[5]);
            uv.w = pk_bf16(p[6], p[7]);
            bf[j][f] = __builtin_bit_cast(short8, uv);
        }
    }
    // owner constants: gates tau for unit u=lane, batch b=w
    float wihc[4], biasc[4];
    #pragma unroll
    for (int t4 = 0; t4 < 4; ++t4) {
        const int g = t4 * 64 + lane;
        wihc[t4]  = W_ih[g];
        biasc[t4] = b_ih[g] + b_hh[g];
    }

    // precomputed addresses (loop-invariant)
    // A-frag reads: lane l -> row m=l15, k-pairs kp = 16f + 4lq + p, swizzled
    const int aw0 = l15 * 32 + ((4 * lq +  0) ^ ((l15 & 7) << 2));
    const int aw1 = l15 * 32 + ((4 * lq + 16) ^ ((l15 & 7) << 2));
    const uintx4* ap0 = (const uintx4*)&hlds[aw0];
    const uintx4* ap1 = (const uintx4*)&hlds[aw1];
    // exch write (lanes<32 hold real batches m = 4*lq + r < 8)
    float* ew0 = &exch[((2 * w + 0) * 16 + l15) * 9 + 4 * lq];
    float* ew1 = &exch[((2 * w + 1) * 16 + l15) * 9 + 4 * lq];
    // owner exch read base: exch[(t4*64+u)*9 + b]
    const float* orp = &exch[lane * 9 + w];
    // owner h write: bf16 at row b=w, col u=lane (swizzled pair word)
    short* hs = (short*)hlds;
    const int hwi = (w * 32 + ((lane >> 1) ^ (w << 2))) * 2 + (lane & 1);

    const floatx4 zero = {0.0f, 0.0f, 0.0f, 0.0f};
    float c = 0.0f, h = 0.0f;
    const float* xrow = x + (long)(b0 + w) * T;

    __syncthreads();

    for (int tb = 0; tb < T; tb += 64) {
        const float xc = xrow[tb + lane];   // owner batch's x chunk, lane=t
        for (int tt = 0; tt < 64; ++tt) {
            // ---- phase 1: A-frags (h of prev step) + MFMA ----
            short8 a0 = __builtin_bit_cast(short8, *ap0);   // k  0..31
            short8 a1 = __builtin_bit_cast(short8, *ap1);   // k 32..63
            floatx4 acc0 = __builtin_amdgcn_mfma_f32_16x16x32_bf16(a0, bf[0][0], zero, 0, 0, 0);
            acc0         = __builtin_amdgcn_mfma_f32_16x16x32_bf16(a1, bf[0][1], acc0, 0, 0, 0);
            floatx4 acc1 = __builtin_amdgcn_mfma_f32_16x16x32_bf16(a0, bf[1][0], zero, 0, 0, 0);
            acc1         = __builtin_amdgcn_mfma_f32_16x16x32_bf16(a1, bf[1][1], acc1, 0, 0, 0);
            // ---- phase 2: scatter raw gates (batches m<8 live in lanes<32) ----
            if (lane < 32) {
                #pragma unroll
                for (int r = 0; r < 4; ++r) ew0[r] = acc0[r];
                #pragma unroll
                for (int r = 0; r < 4; ++r) ew1[r] = acc1[r];
            }
            __syncthreads();
            // ---- phase 3: owner (b=w, u=lane): finish gates, update c/h ----
            const float sx = __builtin_bit_cast(float,
                __builtin_amdgcn_readlane(__builtin_bit_cast(int, xc), tt));
            float gate[4];
            #pragma unroll
            for (int t4 = 0; t4 < 4; ++t4) {
                const float a = orp[t4 * 576] + fmaf(sx, wihc[t4], biasc[t4]);
                const float k = (t4 == 2) ? (2.0f * LOG2E) : (-LOG2E);
                const float rc = __builtin_amdgcn_rcpf(1.0f + __builtin_amdgcn_exp2f(k * a));
                gate[t4] = (t4 == 2) ? fmaf(-2.0f, rc, 1.0f) : rc;
            }
            c = fmaf(gate[1], c, gate[0] * gate[2]);
            h = gate[3] * fast_tanh(c);
            hs[hwi] = (short)(pk_bf16(h, h) & 0xffff);
            __syncthreads();
        }
    }

    // ---- epilogue: out[b,:] = h_T @ W_fc.T + b_fc (wave=batch, lane=unit) ----
    float p0 = h * W_fc[lane];
    float p1 = h * W_fc[64 + lane];
    #pragma unroll
    for (int off = 32; off > 0; off >>= 1) {
        p0 += __shfl_down(p0, off);
        p1 += __shfl_down(p1, off);
    }
    if (lane == 0) {
        out[(b0 + w) * 2 + 0] = p0 + b_fc[0];
        out[(b0 + w) * 2 + 1] = p1 + b_fc[1];
    }
}

extern "C" void kernel_launch(void* const* d_in, const int* in_sizes, int n_in,
                              void* d_out, int out_size, void* d_ws, size_t ws_size,
                              hipStream_t stream) {
    const float* x    = (const float*)d_in[0];
    const float* W_ih = (const float*)d_in[1];
    const float* W_hh = (const float*)d_in[2];
    const float* b_ih = (const float*)d_in[3];
    const float* b_hh = (const float*)d_in[4];
    const float* W_fc = (const float*)d_in[5];
    const float* b_fc = (const float*)d_in[6];
    float* out = (float*)d_out;

    dim3 grid(256);    // 8 batches per block -> 1 block per CU
    dim3 block(512);   // 8 waves
    hipLaunchKernelGGL(lstm_mfma, grid, block, 0, stream,
                       x, W_ih, W_hh, b_ih, b_hh, W_fc, b_fc, out);
}